// Round 5
// baseline (1048.192 us; speedup 1.0000x reference)
//
#include <hip/hip_runtime.h>
#include <hip/hip_bf16.h>
#include <stdint.h>

// MoE top-1: gate -> group by expert -> XCD-grouped dispatch tables ->
// grouped bf16-MFMA GEMMs (counted-vmcnt 2-deep pipeline, conflict-free LDS).
#define N_TOK 4096
#define DIM   768
#define NE    8
#define HDIM  7680
#define ODIM  768
#define G1GRID 2816   // >= 8 * max per-XCD slots for GEMM1 (<=312)
#define G2GRID 1280   // >= 8 * max per-XCD slots for GEMM2 (<=117)

typedef __bf16 bf16x8 __attribute__((ext_vector_type(8)));
typedef float f32x4 __attribute__((ext_vector_type(4)));

__device__ __forceinline__ unsigned short f2bf(float f) {
    union { float f; unsigned u; } v; v.f = f;
    return (unsigned short)((v.u + 0x7fffu + ((v.u >> 16) & 1u)) >> 16);
}

__device__ __forceinline__ unsigned cvt_pk_bf16(float lo, float hi) {
    unsigned r;
    asm("v_cvt_pk_bf16_f32 %0, %1, %2" : "=v"(r) : "v"(lo), "v"(hi));
    return r;
}

__device__ __forceinline__ void gload_lds16(const unsigned short* g, unsigned short* l) {
    __builtin_amdgcn_global_load_lds(
        (const __attribute__((address_space(1))) unsigned int*)g,
        (__attribute__((address_space(3))) unsigned int*)l, 16, 0, 0);
}

// ---------------- gating & prep (validated rounds 1-4) ----------------
__global__ void moe_gating(const float* __restrict__ x, const float* __restrict__ Wg,
                           const float* __restrict__ bg, int* __restrict__ cnt,
                           int* __restrict__ top_e, int* __restrict__ rnk,
                           float* __restrict__ top_p) {
    const int wid  = threadIdx.x >> 6;
    const int lane = threadIdx.x & 63;
    const int t = blockIdx.x * 4 + wid;
    double p[NE];
#pragma unroll
    for (int j = 0; j < NE; ++j) p[j] = 0.0;
    const float* xr  = x  + (size_t)t * DIM + lane * 12;
    const float* wr0 = Wg + lane * 12 * NE;
#pragma unroll
    for (int i = 0; i < 12; ++i) {
        double xv = (double)xr[i];
#pragma unroll
        for (int j = 0; j < NE; ++j) p[j] += xv * (double)wr0[i * NE + j];
    }
#pragma unroll
    for (int off = 32; off >= 1; off >>= 1)
#pragma unroll
        for (int j = 0; j < NE; ++j) p[j] += __shfl_xor(p[j], off, 64);
    if (lane == 0) {
        double l[NE];
#pragma unroll
        for (int j = 0; j < NE; ++j) l[j] = p[j] + (double)bg[j];
        int be = 0; double bl = l[0];
#pragma unroll
        for (int j = 1; j < NE; ++j) if (l[j] > bl) { bl = l[j]; be = j; }
        double s = 0.0;
#pragma unroll
        for (int j = 0; j < NE; ++j) s += exp(l[j] - bl);
        int rk = atomicAdd(&cnt[be], 1);
        top_e[t] = be; rnk[t] = rk; top_p[t] = (float)(1.0 / s);
    }
}

__global__ void moe_init(int* cnt) { if (threadIdx.x < NE) cnt[threadIdx.x] = 0; }

// offs/mc + per-group slot starts (8 parallel per-XCD walks).
// GEMM1 groups p in [0,480): e=p/60, n0=p%60. GEMM2 groups p in [0,192):
// e=p/24, q=p%24, n0=q/4, ks=q%4. Group p -> XCD p%8; members = m-tiles.
__global__ void moe_scan(const int* __restrict__ cnt, int* __restrict__ offs,
                         int* __restrict__ mc, int* __restrict__ g1s,
                         int* __restrict__ g2s) {
    __shared__ int smc[NE];
    int tid = threadIdx.x;
    if (tid == 0) { int s = 0; for (int e = 0; e < NE; ++e) { offs[e] = s; s += cnt[e]; } }
    if (tid < NE) { smc[tid] = (cnt[tid] + 127) >> 7; mc[tid] = smc[tid]; }
    __syncthreads();
    if (tid < 8) {
        int s = 0;
        for (int j = 0; j < 60; ++j) { int p = tid + 8 * j; g1s[p] = s; s += smc[p / 60]; }
        int s2 = 0;
        for (int j = 0; j < 24; ++j) { int p = tid + 8 * j; g2s[p] = s2; s2 += smc[p / 24]; }
    }
}

// Fill dispatch tables: gid -> packed (e<<14)|(mt<<8)|(n0<<2)|ks, or -1.
__global__ void moe_fill(const int* __restrict__ mc, const int* __restrict__ g1s,
                         const int* __restrict__ g2s, int* __restrict__ tbl1,
                         int* __restrict__ tbl2) {
    int gid = blockIdx.x * 256 + threadIdx.x;
    if (gid < G1GRID) {
        int c = gid & 7, slot = gid >> 3;
        int sel = c;
        for (int j = 0; j < 60; ++j) { int p = c + 8 * j; if (g1s[p] <= slot) sel = p; else break; }
        int e = sel / 60, n0 = sel % 60;
        int mt = slot - g1s[sel];
        tbl1[gid] = (mt < mc[e]) ? ((e << 14) | (mt << 8) | (n0 << 2)) : -1;
    } else if (gid < G1GRID + G2GRID) {
        int gg = gid - G1GRID;
        int c = gg & 7, slot = gg >> 3;
        int sel = c;
        for (int j = 0; j < 24; ++j) { int p = c + 8 * j; if (g2s[p] <= slot) sel = p; else break; }
        int e = sel / 24, q = sel % 24;
        int mt = slot - g2s[sel];
        tbl2[gg] = (mt < mc[e]) ? ((e << 14) | (mt << 8) | ((q >> 2) << 2) | (q & 3)) : -1;
    }
}

__global__ void moe_mkperm(const int* __restrict__ top_e, const int* __restrict__ rnk,
                           const float* __restrict__ top_p, const int* __restrict__ offs,
                           int* __restrict__ perm, float* __restrict__ gate_s) {
    int t = blockIdx.x * 256 + threadIdx.x;
    int e = top_e[t];
    int slot = offs[e] + rnk[t];
    perm[slot] = t;
    gate_s[slot] = top_p[t];
}

__global__ void moe_gather(const float* __restrict__ x, const int* __restrict__ perm,
                           unsigned short* __restrict__ Xg) {
    int slot = blockIdx.x;
    int t = perm[slot];
    const float* src = x + (size_t)t * DIM;
    unsigned short* dst = Xg + (size_t)slot * DIM;
    for (int i = threadIdx.x; i < DIM; i += 256) dst[i] = f2bf(src[i]);
}

__global__ void moe_initout(const int* __restrict__ top_e, const float* __restrict__ top_p,
                            const float* __restrict__ b2, float* __restrict__ out) {
    int t = blockIdx.x;
    int e = top_e[t];
    float gv = top_p[t];
    const float* b = b2 + (size_t)e * ODIM;
    float* o = out + (size_t)t * ODIM;
    for (int i = threadIdx.x; i < ODIM; i += 256) o[i] = gv * b[i];
}

// ---------------- grouped GEMM, counted-vmcnt 2-deep pipeline ----------------
// Inner loop identical to round 4 (0 bank conflicts, verified). 1-D grid with
// XCD-grouped table: same-(e,n0,ks) m-tile blocks occupy consecutive slots of
// one XCD's stream -> weight slice (<=983 KB) reused from that XCD's L2.
template<int LAYER>
__global__ __launch_bounds__(256, 4) void moe_gemm(
    const unsigned short* __restrict__ A, const float* __restrict__ B,
    const float* __restrict__ bias, const int* __restrict__ cnt,
    const int* __restrict__ offs, const int* __restrict__ perm,
    const float* __restrict__ gate_s, const int* __restrict__ tbl,
    unsigned short* __restrict__ H, float* __restrict__ out) {

    constexpr int NT    = (LAYER == 1) ? HDIM : ODIM;
    constexpr int AST   = (LAYER == 1) ? DIM  : HDIM;
    constexpr int KFULL = (LAYER == 1) ? DIM  : HDIM;
    constexpr int KBLK  = (LAYER == 1) ? DIM  : HDIM / 4;
    constexpr int NITER = KBLK / 32;              // 24 / 60

    const int code = tbl[blockIdx.x];
    if (code < 0) return;
    const int e  = code >> 14;
    const int mt = (code >> 8) & 63;
    const int n0 = ((code >> 2) & 63) * 128;
    const int ks = code & 3;
    const int ne = cnt[e];
    const int base = offs[e];
    const int mlim = ne - mt * 128;
    const int kbase = ks * KBLK;

    __shared__ unsigned short As[2][4096];
    __shared__ unsigned short Bs[2][4096];

    const int tid = threadIdx.x;
    const int lane = tid & 63, w = tid >> 6;
    const int wr = w >> 1, wc = w & 1;
    const int g = lane >> 4, r = lane & 15;

    const int rl0 = 2 * w * 16 + r;
    const int rl1 = rl0 + 16;
    const int cr0 = rl0 < mlim ? rl0 : mlim - 1;
    const int cr1 = rl1 < mlim ? rl1 : mlim - 1;
    const unsigned short* aS0 = A + (size_t)(base + mt * 128 + cr0) * AST + kbase + g * 8;
    const unsigned short* aS1 = A + (size_t)(base + mt * 128 + cr1) * AST + kbase + g * 8;
    const int aD0 = (2 * w) * 512;
    const int aD1 = aD0 + 512;

    const int bn = tid & 127;
    const int kh = tid >> 7;
    const float* bS = B + (size_t)e * KFULL * NT + (size_t)(kbase + kh * 16) * NT + n0 + bn;
    const int bD = (bn >> 4) * 512 + (kh * 2) * 128 + (bn & 15) * 8;

    f32x4 acc[4][4] = {};
    float bvA[16], bvB[16];

#define FENCE __builtin_amdgcn_sched_barrier(0)

#define LOADB(dst_, t_)                                                        \
    do { const float* bp_ = bS + (size_t)((t_) * 32) * NT;                     \
        _Pragma("unroll")                                                      \
        for (int i_ = 0; i_ < 16; ++i_) dst_[i_] = bp_[(size_t)i_ * NT];       \
    } while (0)

#define DMA_A(t_, buf_)                                                        \
    do { gload_lds16(aS0 + (t_) * 32, &As[buf_][aD0]);                         \
         gload_lds16(aS1 + (t_) * 32, &As[buf_][aD1]); } while (0)

#define COMMITB(src_, buf_)                                                    \
    do { uint4 q0_, q1_;                                                       \
        q0_.x = cvt_pk_bf16(src_[0],  src_[1]);  q0_.y = cvt_pk_bf16(src_[2],  src_[3]);  \
        q0_.z = cvt_pk_bf16(src_[4],  src_[5]);  q0_.w = cvt_pk_bf16(src_[6],  src_[7]);  \
        q1_.x = cvt_pk_bf16(src_[8],  src_[9]);  q1_.y = cvt_pk_bf16(src_[10], src_[11]); \
        q1_.z = cvt_pk_bf16(src_[12], src_[13]); q1_.w = cvt_pk_bf16(src_[14], src_[15]); \
        *(uint4*)&Bs[buf_][bD]       = q0_;                                    \
        *(uint4*)&Bs[buf_][bD + 128] = q1_;                                    \
    } while (0)

#define BODY(t_, cur_, LDst_, CMsrc_, MODE_)                                   \
    do {                                                                       \
        bf16x8 af_[4], bf_[4];                                                 \
        _Pragma("unroll")                                                      \
        for (int m_ = 0; m_ < 4; ++m_)                                         \
            af_[m_] = *(const bf16x8*)&As[cur_][(wr * 4 + m_) * 512 + lane * 8]; \
        _Pragma("unroll")                                                      \
        for (int n_ = 0; n_ < 4; ++n_)                                         \
            bf_[n_] = *(const bf16x8*)&Bs[cur_][(wc * 4 + n_) * 512 + lane * 8]; \
        FENCE;                                                                 \
        if (MODE_ >= 1) DMA_A((t_) + 1, (cur_) ^ 1);                           \
        FENCE;                                                                 \
        if (MODE_ == 2) LOADB(LDst_, (t_) + 2);                                \
        asm volatile("s_waitcnt lgkmcnt(0)" ::: "memory");                     \
        FENCE;                                                                 \
        _Pragma("unroll")                                                      \
        for (int n_ = 0; n_ < 4; ++n_)                                         \
            _Pragma("unroll")                                                  \
            for (int m_ = 0; m_ < 4; ++m_)                                     \
                acc[m_][n_] = __builtin_amdgcn_mfma_f32_16x16x32_bf16(         \
                    af_[m_], bf_[n_], acc[m_][n_], 0, 0, 0);                   \
        FENCE;                                                                 \
        if (MODE_ == 2) { asm volatile("s_waitcnt vmcnt(16)" ::: "memory"); }  \
        else if (MODE_ == 1) { asm volatile("s_waitcnt vmcnt(0)" ::: "memory"); } \
        if (MODE_ >= 1) {                                                      \
            COMMITB(CMsrc_, (cur_) ^ 1);                                       \
            asm volatile("s_waitcnt lgkmcnt(0)" ::: "memory");                 \
            __builtin_amdgcn_s_barrier();                                      \
            FENCE;                                                             \
        }                                                                      \
    } while (0)

    LOADB(bvA, 0);
    FENCE;
    DMA_A(0, 0);
    FENCE;
    LOADB(bvB, 1);
    asm volatile("s_waitcnt vmcnt(16)" ::: "memory");
    FENCE;
    COMMITB(bvA, 0);
    asm volatile("s_waitcnt lgkmcnt(0)" ::: "memory");
    __builtin_amdgcn_s_barrier();
    FENCE;

#pragma unroll 1
    for (int t = 0; t + 4 <= NITER; t += 2) {
        BODY(t,     0, bvA, bvB, 2);
        BODY(t + 1, 1, bvB, bvA, 2);
    }
    BODY(NITER - 2, 0, bvA, bvB, 1);
    BODY(NITER - 1, 1, bvB, bvA, 0);

#undef BODY
#undef COMMITB
#undef DMA_A
#undef LOADB
#undef FENCE

    // epilogue: C/D layout col = lane&15 (=r), row = 4*(lane>>4) (=4g) + reg
#pragma unroll
    for (int m = 0; m < 4; ++m) {
#pragma unroll
        for (int j = 0; j < 4; ++j) {
            int lrow = mt * 128 + wr * 64 + m * 16 + g * 4 + j;
            if (lrow < ne) {
                int slot = base + lrow;
#pragma unroll
                for (int n = 0; n < 4; ++n) {
                    int col = n0 + wc * 64 + n * 16 + r;
                    if constexpr (LAYER == 1) {
                        float v = acc[m][n][j] + bias[(size_t)e * NT + col];
                        v = fmaxf(v, 0.0f);
                        H[(size_t)slot * HDIM + col] = f2bf(v);
                    } else {
                        atomicAdd(&out[(size_t)perm[slot] * ODIM + col],
                                  gate_s[slot] * acc[m][n][j]);
                    }
                }
            }
        }
    }
}

// ---------------- launch ----------------
extern "C" void kernel_launch(void* const* d_in, const int* in_sizes, int n_in,
                              void* d_out, int out_size, void* d_ws, size_t ws_size,
                              hipStream_t stream) {
    const float* x  = (const float*)d_in[0];
    const float* Wg = (const float*)d_in[1];
    const float* bg = (const float*)d_in[2];
    const float* W1 = (const float*)d_in[3];
    const float* b1 = (const float*)d_in[4];
    const float* W2 = (const float*)d_in[5];
    const float* b2 = (const float*)d_in[6];
    float* out = (float*)d_out;

    char* ws = (char*)d_ws;
    int*   cnt    = (int*)(ws + 0);
    int*   offs   = (int*)(ws + 64);
    int*   mc     = (int*)(ws + 128);
    int*   g1s    = (int*)(ws + 256);              // 480 ints
    int*   g2s    = (int*)(ws + 2304);             // 192 ints
    int*   tbl1   = (int*)(ws + 3072);             // 2816 ints
    int*   tbl2   = (int*)(ws + 14336);            // 1280 ints
    int*   top_e  = (int*)(ws + 19456);
    int*   rnk    = (int*)(ws + 19456 + 16384);
    float* top_p  = (float*)(ws + 19456 + 2 * 16384);
    int*   perm   = (int*)(ws + 19456 + 3 * 16384);
    float* gate_s = (float*)(ws + 19456 + 4 * 16384);
    unsigned short* Xg = (unsigned short*)(ws + 101376);
    unsigned short* H  = (unsigned short*)(ws + 101376 + (size_t)N_TOK * DIM * 2);
    // total ws: ~69.3 MB

    moe_init<<<1, 64, 0, stream>>>(cnt);
    moe_gating<<<N_TOK / 4, 256, 0, stream>>>(x, Wg, bg, cnt, top_e, rnk, top_p);
    moe_scan<<<1, 64, 0, stream>>>(cnt, offs, mc, g1s, g2s);
    moe_fill<<<(G1GRID + G2GRID) / 256, 256, 0, stream>>>(mc, g1s, g2s, tbl1, tbl2);
    moe_mkperm<<<N_TOK / 256, 256, 0, stream>>>(top_e, rnk, top_p, offs, perm, gate_s);
    moe_gather<<<N_TOK, 256, 0, stream>>>(x, perm, Xg);
    moe_initout<<<N_TOK, 256, 0, stream>>>(top_e, top_p, b2, out);

    moe_gemm<1><<<G1GRID, 256, 0, stream>>>(Xg, W1, b1, cnt, offs, perm, gate_s, tbl1, H, out);
    moe_gemm<2><<<G2GRID, 256, 0, stream>>>(H, W2, b2, cnt, offs, perm, gate_s, tbl2, H, out);
}

// Round 6
// 371.753 us; speedup vs baseline: 2.8196x; 2.8196x over previous
//
#include <hip/hip_runtime.h>
#include <hip/hip_bf16.h>
#include <stdint.h>

// MoE top-1: gate -> group by expert -> XCD-grouped dispatch tables ->
// grouped bf16-MFMA GEMMs (counted-vmcnt 2-deep pipeline, conflict-free LDS).
// Round 6: launch_bounds back to (256,3) [4 caused unified VGPR+AGPR budget
// 128/wave -> B-prefetch regs spilled to scratch: WRITE_SIZE 49->529MB, 3x slow].
// GEMM2 groups now (e,n0) with ks-major members: K-split atomics XCD-local.
#define N_TOK 4096
#define DIM   768
#define NE    8
#define HDIM  7680
#define ODIM  768
#define G1GRID 2816   // 8 XCDs x 352 slots >= 8 * max-per-XCD (320)
#define G2GRID 1344   // 8 XCDs x 168 slots >= 8 * max-per-XCD (160)

typedef __bf16 bf16x8 __attribute__((ext_vector_type(8)));
typedef float f32x4 __attribute__((ext_vector_type(4)));

__device__ __forceinline__ unsigned short f2bf(float f) {
    union { float f; unsigned u; } v; v.f = f;
    return (unsigned short)((v.u + 0x7fffu + ((v.u >> 16) & 1u)) >> 16);
}

__device__ __forceinline__ unsigned cvt_pk_bf16(float lo, float hi) {
    unsigned r;
    asm("v_cvt_pk_bf16_f32 %0, %1, %2" : "=v"(r) : "v"(lo), "v"(hi));
    return r;
}

__device__ __forceinline__ void gload_lds16(const unsigned short* g, unsigned short* l) {
    __builtin_amdgcn_global_load_lds(
        (const __attribute__((address_space(1))) unsigned int*)g,
        (__attribute__((address_space(3))) unsigned int*)l, 16, 0, 0);
}

// ---------------- gating & prep (validated rounds 1-5) ----------------
__global__ void moe_gating(const float* __restrict__ x, const float* __restrict__ Wg,
                           const float* __restrict__ bg, int* __restrict__ cnt,
                           int* __restrict__ top_e, int* __restrict__ rnk,
                           float* __restrict__ top_p) {
    const int wid  = threadIdx.x >> 6;
    const int lane = threadIdx.x & 63;
    const int t = blockIdx.x * 4 + wid;
    double p[NE];
#pragma unroll
    for (int j = 0; j < NE; ++j) p[j] = 0.0;
    const float* xr  = x  + (size_t)t * DIM + lane * 12;
    const float* wr0 = Wg + lane * 12 * NE;
#pragma unroll
    for (int i = 0; i < 12; ++i) {
        double xv = (double)xr[i];
#pragma unroll
        for (int j = 0; j < NE; ++j) p[j] += xv * (double)wr0[i * NE + j];
    }
#pragma unroll
    for (int off = 32; off >= 1; off >>= 1)
#pragma unroll
        for (int j = 0; j < NE; ++j) p[j] += __shfl_xor(p[j], off, 64);
    if (lane == 0) {
        double l[NE];
#pragma unroll
        for (int j = 0; j < NE; ++j) l[j] = p[j] + (double)bg[j];
        int be = 0; double bl = l[0];
#pragma unroll
        for (int j = 1; j < NE; ++j) if (l[j] > bl) { bl = l[j]; be = j; }
        double s = 0.0;
#pragma unroll
        for (int j = 0; j < NE; ++j) s += exp(l[j] - bl);
        int rk = atomicAdd(&cnt[be], 1);
        top_e[t] = be; rnk[t] = rk; top_p[t] = (float)(1.0 / s);
    }
}

__global__ void moe_init(int* cnt) { if (threadIdx.x < NE) cnt[threadIdx.x] = 0; }

// offs/mc + per-XCD slot starts.
// GEMM1: 480 groups p: e=p/60, n0=p%60; members = mt (mc[e] of them). XCD p%8.
// GEMM2: 48 groups  p: e=p/6,  n0=p%6;  members = ks*mc[e]+mt (4*mc[e]). XCD p%8.
__global__ void moe_scan(const int* __restrict__ cnt, int* __restrict__ offs,
                         int* __restrict__ mc, int* __restrict__ g1s,
                         int* __restrict__ g2s) {
    __shared__ int smc[NE];
    int tid = threadIdx.x;
    if (tid == 0) { int s = 0; for (int e = 0; e < NE; ++e) { offs[e] = s; s += cnt[e]; } }
    if (tid < NE) { smc[tid] = (cnt[tid] + 127) >> 7; mc[tid] = smc[tid]; }
    __syncthreads();
    if (tid < 8) {
        int s = 0;
        for (int j = 0; j < 60; ++j) { int p = tid + 8 * j; g1s[p] = s; s += smc[p / 60]; }
        int s2 = 0;
        for (int j = 0; j < 6; ++j)  { int p = tid + 8 * j; g2s[p] = s2; s2 += 4 * smc[p / 6]; }
    }
}

// Fill dispatch tables: gid -> packed (e<<14)|(mt<<8)|(n0<<2)|ks, or -1.
__global__ void moe_fill(const int* __restrict__ mc, const int* __restrict__ g1s,
                         const int* __restrict__ g2s, int* __restrict__ tbl1,
                         int* __restrict__ tbl2) {
    int gid = blockIdx.x * 256 + threadIdx.x;
    if (gid < G1GRID) {
        int c = gid & 7, slot = gid >> 3;
        int sel = c;
        for (int j = 0; j < 60; ++j) { int p = c + 8 * j; if (g1s[p] <= slot) sel = p; else break; }
        int e = sel / 60, n0 = sel % 60;
        int mt = slot - g1s[sel];
        tbl1[gid] = (mt < mc[e]) ? ((e << 14) | (mt << 8) | (n0 << 2)) : -1;
    } else if (gid < G1GRID + G2GRID) {
        int gg = gid - G1GRID;
        int c = gg & 7, slot = gg >> 3;
        int sel = c;
        for (int j = 0; j < 6; ++j) { int p = c + 8 * j; if (g2s[p] <= slot) sel = p; else break; }
        int e = sel / 6, n0 = sel % 6;
        int mem = slot - g2s[sel];
        int mcE = mc[e];
        int ks = mem / mcE, mt = mem - ks * mcE;   // ks-major: same-ks mt adjacent
        tbl2[gg] = (mem < 4 * mcE) ? ((e << 14) | (mt << 8) | (n0 << 2) | ks) : -1;
    }
}

__global__ void moe_mkperm(const int* __restrict__ top_e, const int* __restrict__ rnk,
                           const float* __restrict__ top_p, const int* __restrict__ offs,
                           int* __restrict__ perm, float* __restrict__ gate_s) {
    int t = blockIdx.x * 256 + threadIdx.x;
    int e = top_e[t];
    int slot = offs[e] + rnk[t];
    perm[slot] = t;
    gate_s[slot] = top_p[t];
}

__global__ void moe_gather(const float* __restrict__ x, const int* __restrict__ perm,
                           unsigned short* __restrict__ Xg) {
    int slot = blockIdx.x;
    int t = perm[slot];
    const float* src = x + (size_t)t * DIM;
    unsigned short* dst = Xg + (size_t)slot * DIM;
    for (int i = threadIdx.x; i < DIM; i += 256) dst[i] = f2bf(src[i]);
}

__global__ void moe_initout(const int* __restrict__ top_e, const float* __restrict__ top_p,
                            const float* __restrict__ b2, float* __restrict__ out) {
    int t = blockIdx.x;
    int e = top_e[t];
    float gv = top_p[t];
    const float* b = b2 + (size_t)e * ODIM;
    float* o = out + (size_t)t * ODIM;
    for (int i = threadIdx.x; i < ODIM; i += 256) o[i] = gv * b[i];
}

// ---------------- grouped GEMM, counted-vmcnt 2-deep pipeline ----------------
// Inner loop identical to rounds 4/5 (0 bank conflicts). 1-D grid, XCD tables.
template<int LAYER>
__global__ __launch_bounds__(256, 3) void moe_gemm(
    const unsigned short* __restrict__ A, const float* __restrict__ B,
    const float* __restrict__ bias, const int* __restrict__ cnt,
    const int* __restrict__ offs, const int* __restrict__ perm,
    const float* __restrict__ gate_s, const int* __restrict__ tbl,
    unsigned short* __restrict__ H, float* __restrict__ out) {

    constexpr int NT    = (LAYER == 1) ? HDIM : ODIM;
    constexpr int AST   = (LAYER == 1) ? DIM  : HDIM;
    constexpr int KFULL = (LAYER == 1) ? DIM  : HDIM;
    constexpr int KBLK  = (LAYER == 1) ? DIM  : HDIM / 4;
    constexpr int NITER = KBLK / 32;              // 24 / 60

    const int code = tbl[blockIdx.x];
    if (code < 0) return;
    const int e  = code >> 14;
    const int mt = (code >> 8) & 63;
    const int n0 = ((code >> 2) & 63) * 128;
    const int ks = code & 3;
    const int ne = cnt[e];
    const int base = offs[e];
    const int mlim = ne - mt * 128;
    const int kbase = ks * KBLK;

    __shared__ unsigned short As[2][4096];
    __shared__ unsigned short Bs[2][4096];

    const int tid = threadIdx.x;
    const int lane = tid & 63, w = tid >> 6;
    const int wr = w >> 1, wc = w & 1;
    const int g = lane >> 4, r = lane & 15;

    const int rl0 = 2 * w * 16 + r;
    const int rl1 = rl0 + 16;
    const int cr0 = rl0 < mlim ? rl0 : mlim - 1;
    const int cr1 = rl1 < mlim ? rl1 : mlim - 1;
    const unsigned short* aS0 = A + (size_t)(base + mt * 128 + cr0) * AST + kbase + g * 8;
    const unsigned short* aS1 = A + (size_t)(base + mt * 128 + cr1) * AST + kbase + g * 8;
    const int aD0 = (2 * w) * 512;
    const int aD1 = aD0 + 512;

    const int bn = tid & 127;
    const int kh = tid >> 7;
    const float* bS = B + (size_t)e * KFULL * NT + (size_t)(kbase + kh * 16) * NT + n0 + bn;
    const int bD = (bn >> 4) * 512 + (kh * 2) * 128 + (bn & 15) * 8;

    f32x4 acc[4][4] = {};
    float bvA[16], bvB[16];

#define FENCE __builtin_amdgcn_sched_barrier(0)

#define LOADB(dst_, t_)                                                        \
    do { const float* bp_ = bS + (size_t)((t_) * 32) * NT;                     \
        _Pragma("unroll")                                                      \
        for (int i_ = 0; i_ < 16; ++i_) dst_[i_] = bp_[(size_t)i_ * NT];       \
    } while (0)

#define DMA_A(t_, buf_)                                                        \
    do { gload_lds16(aS0 + (t_) * 32, &As[buf_][aD0]);                         \
         gload_lds16(aS1 + (t_) * 32, &As[buf_][aD1]); } while (0)

#define COMMITB(src_, buf_)                                                    \
    do { uint4 q0_, q1_;                                                       \
        q0_.x = cvt_pk_bf16(src_[0],  src_[1]);  q0_.y = cvt_pk_bf16(src_[2],  src_[3]);  \
        q0_.z = cvt_pk_bf16(src_[4],  src_[5]);  q0_.w = cvt_pk_bf16(src_[6],  src_[7]);  \
        q1_.x = cvt_pk_bf16(src_[8],  src_[9]);  q1_.y = cvt_pk_bf16(src_[10], src_[11]); \
        q1_.z = cvt_pk_bf16(src_[12], src_[13]); q1_.w = cvt_pk_bf16(src_[14], src_[15]); \
        *(uint4*)&Bs[buf_][bD]       = q0_;                                    \
        *(uint4*)&Bs[buf_][bD + 128] = q1_;                                    \
    } while (0)

#define BODY(t_, cur_, LDst_, CMsrc_, MODE_)                                   \
    do {                                                                       \
        bf16x8 af_[4], bf_[4];                                                 \
        _Pragma("unroll")                                                      \
        for (int m_ = 0; m_ < 4; ++m_)                                         \
            af_[m_] = *(const bf16x8*)&As[cur_][(wr * 4 + m_) * 512 + lane * 8]; \
        _Pragma("unroll")                                                      \
        for (int n_ = 0; n_ < 4; ++n_)                                         \
            bf_[n_] = *(const bf16x8*)&Bs[cur_][(wc * 4 + n_) * 512 + lane * 8]; \
        FENCE;                                                                 \
        if (MODE_ >= 1) DMA_A((t_) + 1, (cur_) ^ 1);                           \
        FENCE;                                                                 \
        if (MODE_ == 2) LOADB(LDst_, (t_) + 2);                                \
        asm volatile("s_waitcnt lgkmcnt(0)" ::: "memory");                     \
        FENCE;                                                                 \
        _Pragma("unroll")                                                      \
        for (int n_ = 0; n_ < 4; ++n_)                                         \
            _Pragma("unroll")                                                  \
            for (int m_ = 0; m_ < 4; ++m_)                                     \
                acc[m_][n_] = __builtin_amdgcn_mfma_f32_16x16x32_bf16(         \
                    af_[m_], bf_[n_], acc[m_][n_], 0, 0, 0);                   \
        FENCE;                                                                 \
        if (MODE_ == 2) { asm volatile("s_waitcnt vmcnt(16)" ::: "memory"); }  \
        else if (MODE_ == 1) { asm volatile("s_waitcnt vmcnt(0)" ::: "memory"); } \
        if (MODE_ >= 1) {                                                      \
            COMMITB(CMsrc_, (cur_) ^ 1);                                       \
            asm volatile("s_waitcnt lgkmcnt(0)" ::: "memory");                 \
            __builtin_amdgcn_s_barrier();                                      \
            FENCE;                                                             \
        }                                                                      \
    } while (0)

    LOADB(bvA, 0);
    FENCE;
    DMA_A(0, 0);
    FENCE;
    LOADB(bvB, 1);
    asm volatile("s_waitcnt vmcnt(16)" ::: "memory");
    FENCE;
    COMMITB(bvA, 0);
    asm volatile("s_waitcnt lgkmcnt(0)" ::: "memory");
    __builtin_amdgcn_s_barrier();
    FENCE;

#pragma unroll 1
    for (int t = 0; t + 4 <= NITER; t += 2) {
        BODY(t,     0, bvA, bvB, 2);
        BODY(t + 1, 1, bvB, bvA, 2);
    }
    BODY(NITER - 2, 0, bvA, bvB, 1);
    BODY(NITER - 1, 1, bvB, bvA, 0);

#undef BODY
#undef COMMITB
#undef DMA_A
#undef LOADB
#undef FENCE

    // epilogue: C/D layout col = lane&15 (=r), row = 4*(lane>>4) (=4g) + reg
#pragma unroll
    for (int m = 0; m < 4; ++m) {
#pragma unroll
        for (int j = 0; j < 4; ++j) {
            int lrow = mt * 128 + wr * 64 + m * 16 + g * 4 + j;
            if (lrow < ne) {
                int slot = base + lrow;
#pragma unroll
                for (int n = 0; n < 4; ++n) {
                    int col = n0 + wc * 64 + n * 16 + r;
                    if constexpr (LAYER == 1) {
                        float v = acc[m][n][j] + bias[(size_t)e * NT + col];
                        v = fmaxf(v, 0.0f);
                        H[(size_t)slot * HDIM + col] = f2bf(v);
                    } else {
                        atomicAdd(&out[(size_t)perm[slot] * ODIM + col],
                                  gate_s[slot] * acc[m][n][j]);
                    }
                }
            }
        }
    }
}

// ---------------- launch ----------------
extern "C" void kernel_launch(void* const* d_in, const int* in_sizes, int n_in,
                              void* d_out, int out_size, void* d_ws, size_t ws_size,
                              hipStream_t stream) {
    const float* x  = (const float*)d_in[0];
    const float* Wg = (const float*)d_in[1];
    const float* bg = (const float*)d_in[2];
    const float* W1 = (const float*)d_in[3];
    const float* b1 = (const float*)d_in[4];
    const float* W2 = (const float*)d_in[5];
    const float* b2 = (const float*)d_in[6];
    float* out = (float*)d_out;

    char* ws = (char*)d_ws;
    int*   cnt    = (int*)(ws + 0);
    int*   offs   = (int*)(ws + 64);
    int*   mc     = (int*)(ws + 128);
    int*   g1s    = (int*)(ws + 256);              // 480 ints
    int*   g2s    = (int*)(ws + 2304);             // 48 ints
    int*   tbl1   = (int*)(ws + 3072);             // 2816 ints
    int*   tbl2   = (int*)(ws + 14336);            // 1344 ints
    int*   top_e  = (int*)(ws + 19712);
    int*   rnk    = (int*)(ws + 19712 + 16384);
    float* top_p  = (float*)(ws + 19712 + 2 * 16384);
    int*   perm   = (int*)(ws + 19712 + 3 * 16384);
    float* gate_s = (float*)(ws + 19712 + 4 * 16384);
    unsigned short* Xg = (unsigned short*)(ws + 101632);
    unsigned short* H  = (unsigned short*)(ws + 101632 + (size_t)N_TOK * DIM * 2);
    // total ws: ~69.3 MB

    moe_init<<<1, 64, 0, stream>>>(cnt);
    moe_gating<<<N_TOK / 4, 256, 0, stream>>>(x, Wg, bg, cnt, top_e, rnk, top_p);
    moe_scan<<<1, 64, 0, stream>>>(cnt, offs, mc, g1s, g2s);
    moe_fill<<<(G1GRID + G2GRID + 255) / 256, 256, 0, stream>>>(mc, g1s, g2s, tbl1, tbl2);
    moe_mkperm<<<N_TOK / 256, 256, 0, stream>>>(top_e, rnk, top_p, offs, perm, gate_s);
    moe_gather<<<N_TOK, 256, 0, stream>>>(x, perm, Xg);
    moe_initout<<<N_TOK, 256, 0, stream>>>(top_e, top_p, b2, out);

    moe_gemm<1><<<G1GRID, 256, 0, stream>>>(Xg, W1, b1, cnt, offs, perm, gate_s, tbl1, H, out);
    moe_gemm<2><<<G2GRID, 256, 0, stream>>>(H, W2, b2, cnt, offs, perm, gate_s, tbl2, H, out);
}

// Round 7
// 367.767 us; speedup vs baseline: 2.8502x; 1.0108x over previous
//
#include <hip/hip_runtime.h>
#include <hip/hip_bf16.h>
#include <stdint.h>

// MoE top-1: gate -> group by expert -> XCD-grouped dispatch tables ->
// grouped bf16-MFMA GEMMs. Round 7: A-staging made 2 iters deep (triple-
// buffered As + DMA(t+2)), steady wait vmcnt(18) retires only loads issued
// one full iteration earlier -> per-iter exposed DMA latency removed.
// (r6 waited on a DMA issued the same iteration: MfmaUtil 13.8%, all idle.)
#define N_TOK 4096
#define DIM   768
#define NE    8
#define HDIM  7680
#define ODIM  768
#define G1GRID 2816   // 8 XCDs x 352 slots >= 8 * max-per-XCD (320)
#define G2GRID 1344   // 8 XCDs x 168 slots >= 8 * max-per-XCD (160)

typedef __bf16 bf16x8 __attribute__((ext_vector_type(8)));
typedef float f32x4 __attribute__((ext_vector_type(4)));

__device__ __forceinline__ unsigned short f2bf(float f) {
    union { float f; unsigned u; } v; v.f = f;
    return (unsigned short)((v.u + 0x7fffu + ((v.u >> 16) & 1u)) >> 16);
}

__device__ __forceinline__ unsigned cvt_pk_bf16(float lo, float hi) {
    unsigned r;
    asm("v_cvt_pk_bf16_f32 %0, %1, %2" : "=v"(r) : "v"(lo), "v"(hi));
    return r;
}

__device__ __forceinline__ void gload_lds16(const unsigned short* g, unsigned short* l) {
    __builtin_amdgcn_global_load_lds(
        (const __attribute__((address_space(1))) unsigned int*)g,
        (__attribute__((address_space(3))) unsigned int*)l, 16, 0, 0);
}

// ---------------- gating & prep (validated rounds 1-6) ----------------
__global__ void moe_gating(const float* __restrict__ x, const float* __restrict__ Wg,
                           const float* __restrict__ bg, int* __restrict__ cnt,
                           int* __restrict__ top_e, int* __restrict__ rnk,
                           float* __restrict__ top_p) {
    const int wid  = threadIdx.x >> 6;
    const int lane = threadIdx.x & 63;
    const int t = blockIdx.x * 4 + wid;
    double p[NE];
#pragma unroll
    for (int j = 0; j < NE; ++j) p[j] = 0.0;
    const float* xr  = x  + (size_t)t * DIM + lane * 12;
    const float* wr0 = Wg + lane * 12 * NE;
#pragma unroll
    for (int i = 0; i < 12; ++i) {
        double xv = (double)xr[i];
#pragma unroll
        for (int j = 0; j < NE; ++j) p[j] += xv * (double)wr0[i * NE + j];
    }
#pragma unroll
    for (int off = 32; off >= 1; off >>= 1)
#pragma unroll
        for (int j = 0; j < NE; ++j) p[j] += __shfl_xor(p[j], off, 64);
    if (lane == 0) {
        double l[NE];
#pragma unroll
        for (int j = 0; j < NE; ++j) l[j] = p[j] + (double)bg[j];
        int be = 0; double bl = l[0];
#pragma unroll
        for (int j = 1; j < NE; ++j) if (l[j] > bl) { bl = l[j]; be = j; }
        double s = 0.0;
#pragma unroll
        for (int j = 0; j < NE; ++j) s += exp(l[j] - bl);
        int rk = atomicAdd(&cnt[be], 1);
        top_e[t] = be; rnk[t] = rk; top_p[t] = (float)(1.0 / s);
    }
}

__global__ void moe_init(int* cnt) { if (threadIdx.x < NE) cnt[threadIdx.x] = 0; }

// offs/mc + per-XCD slot starts.
// GEMM1: 480 groups p: e=p/60, n0=p%60; members = mt (mc[e] of them). XCD p%8.
// GEMM2: 48 groups  p: e=p/6,  n0=p%6;  members = ks*mc[e]+mt (4*mc[e]). XCD p%8.
__global__ void moe_scan(const int* __restrict__ cnt, int* __restrict__ offs,
                         int* __restrict__ mc, int* __restrict__ g1s,
                         int* __restrict__ g2s) {
    __shared__ int smc[NE];
    int tid = threadIdx.x;
    if (tid == 0) { int s = 0; for (int e = 0; e < NE; ++e) { offs[e] = s; s += cnt[e]; } }
    if (tid < NE) { smc[tid] = (cnt[tid] + 127) >> 7; mc[tid] = smc[tid]; }
    __syncthreads();
    if (tid < 8) {
        int s = 0;
        for (int j = 0; j < 60; ++j) { int p = tid + 8 * j; g1s[p] = s; s += smc[p / 60]; }
        int s2 = 0;
        for (int j = 0; j < 6; ++j)  { int p = tid + 8 * j; g2s[p] = s2; s2 += 4 * smc[p / 6]; }
    }
}

// Fill dispatch tables: gid -> packed (e<<14)|(mt<<8)|(n0<<2)|ks, or -1.
__global__ void moe_fill(const int* __restrict__ mc, const int* __restrict__ g1s,
                         const int* __restrict__ g2s, int* __restrict__ tbl1,
                         int* __restrict__ tbl2) {
    int gid = blockIdx.x * 256 + threadIdx.x;
    if (gid < G1GRID) {
        int c = gid & 7, slot = gid >> 3;
        int sel = c;
        for (int j = 0; j < 60; ++j) { int p = c + 8 * j; if (g1s[p] <= slot) sel = p; else break; }
        int e = sel / 60, n0 = sel % 60;
        int mt = slot - g1s[sel];
        tbl1[gid] = (mt < mc[e]) ? ((e << 14) | (mt << 8) | (n0 << 2)) : -1;
    } else if (gid < G1GRID + G2GRID) {
        int gg = gid - G1GRID;
        int c = gg & 7, slot = gg >> 3;
        int sel = c;
        for (int j = 0; j < 6; ++j) { int p = c + 8 * j; if (g2s[p] <= slot) sel = p; else break; }
        int e = sel / 6, n0 = sel % 6;
        int mem = slot - g2s[sel];
        int mcE = mc[e];
        int ks = mem / mcE, mt = mem - ks * mcE;   // ks-major: same-ks mt adjacent
        tbl2[gg] = (mem < 4 * mcE) ? ((e << 14) | (mt << 8) | (n0 << 2) | ks) : -1;
    }
}

__global__ void moe_mkperm(const int* __restrict__ top_e, const int* __restrict__ rnk,
                           const float* __restrict__ top_p, const int* __restrict__ offs,
                           int* __restrict__ perm, float* __restrict__ gate_s) {
    int t = blockIdx.x * 256 + threadIdx.x;
    int e = top_e[t];
    int slot = offs[e] + rnk[t];
    perm[slot] = t;
    gate_s[slot] = top_p[t];
}

__global__ void moe_gather(const float* __restrict__ x, const int* __restrict__ perm,
                           unsigned short* __restrict__ Xg) {
    int slot = blockIdx.x;
    int t = perm[slot];
    const float* src = x + (size_t)t * DIM;
    unsigned short* dst = Xg + (size_t)slot * DIM;
    for (int i = threadIdx.x; i < DIM; i += 256) dst[i] = f2bf(src[i]);
}

__global__ void moe_initout(const int* __restrict__ top_e, const float* __restrict__ top_p,
                            const float* __restrict__ b2, float* __restrict__ out) {
    int t = blockIdx.x;
    int e = top_e[t];
    float gv = top_p[t];
    const float* b = b2 + (size_t)e * ODIM;
    float* o = out + (size_t)t * ODIM;
    for (int i = threadIdx.x; i < ODIM; i += 256) o[i] = gv * b[i];
}

// ---------------- grouped GEMM, 2-iter-deep counted-vmcnt pipeline ----------------
// 128x128 tile, BK=32, 4 waves (2x2). LDS: A triple-buffered (DMA 2 ahead),
// B double-buffered (regs 2 ahead). Frag reads lane-linear: 0 bank conflicts.
// Steady iter t: ds_read frags(A[t%3], Bs[cur]) | DMA A(t+2) | load B(t+2)->regs
//   | lgkmcnt(0) | 64 MFMA | vmcnt(18) [retires DMA(t+1)+B(t+1), issued LAST
//   iter -> full-iteration latency cover] | commit B(t+1) | lgkm | barrier.
template<int LAYER>
__global__ __launch_bounds__(256, 3) void moe_gemm(
    const unsigned short* __restrict__ A, const float* __restrict__ B,
    const float* __restrict__ bias, const int* __restrict__ cnt,
    const int* __restrict__ offs, const int* __restrict__ perm,
    const float* __restrict__ gate_s, const int* __restrict__ tbl,
    unsigned short* __restrict__ H, float* __restrict__ out) {

    constexpr int NT    = (LAYER == 1) ? HDIM : ODIM;
    constexpr int AST   = (LAYER == 1) ? DIM  : HDIM;
    constexpr int KFULL = (LAYER == 1) ? DIM  : HDIM;
    constexpr int KBLK  = (LAYER == 1) ? DIM  : HDIM / 4;
    constexpr int NITER = KBLK / 32;              // 24 / 60 (even, >=4)

    const int code = tbl[blockIdx.x];
    if (code < 0) return;
    const int e  = code >> 14;
    const int mt = (code >> 8) & 63;
    const int n0 = ((code >> 2) & 63) * 128;
    const int ks = code & 3;
    const int ne = cnt[e];
    const int base = offs[e];
    const int mlim = ne - mt * 128;
    const int kbase = ks * KBLK;

    __shared__ unsigned short As[3][4096];
    __shared__ unsigned short Bs[2][4096];

    const int tid = threadIdx.x;
    const int lane = tid & 63, w = tid >> 6;
    const int wr = w >> 1, wc = w & 1;
    const int g = lane >> 4, r = lane & 15;

    const int rl0 = 2 * w * 16 + r;
    const int rl1 = rl0 + 16;
    const int cr0 = rl0 < mlim ? rl0 : mlim - 1;
    const int cr1 = rl1 < mlim ? rl1 : mlim - 1;
    const unsigned short* aS0 = A + (size_t)(base + mt * 128 + cr0) * AST + kbase + g * 8;
    const unsigned short* aS1 = A + (size_t)(base + mt * 128 + cr1) * AST + kbase + g * 8;
    const int aD0 = (2 * w) * 512;
    const int aD1 = aD0 + 512;

    const int bn = tid & 127;
    const int kh = tid >> 7;
    const float* bS = B + (size_t)e * KFULL * NT + (size_t)(kbase + kh * 16) * NT + n0 + bn;
    const int bD = (bn >> 4) * 512 + (kh * 2) * 128 + (bn & 15) * 8;

    f32x4 acc[4][4] = {};
    float bvA[16], bvB[16];

    unsigned short* A0 = &As[0][0];
    unsigned short* A1 = &As[1][0];
    unsigned short* A2 = &As[2][0];

#define FENCE __builtin_amdgcn_sched_barrier(0)

#define LOADB(dst_, t_)                                                        \
    do { const float* bp_ = bS + (size_t)((t_) * 32) * NT;                     \
        _Pragma("unroll")                                                      \
        for (int i_ = 0; i_ < 16; ++i_) dst_[i_] = bp_[(size_t)i_ * NT];       \
    } while (0)

#define DMA_A(t_, abase_)                                                      \
    do { gload_lds16(aS0 + (t_) * 32, (abase_) + aD0);                         \
         gload_lds16(aS1 + (t_) * 32, (abase_) + aD1); } while (0)

#define COMMITB(src_, buf_)                                                    \
    do { uint4 q0_, q1_;                                                       \
        q0_.x = cvt_pk_bf16(src_[0],  src_[1]);  q0_.y = cvt_pk_bf16(src_[2],  src_[3]);  \
        q0_.z = cvt_pk_bf16(src_[4],  src_[5]);  q0_.w = cvt_pk_bf16(src_[6],  src_[7]);  \
        q1_.x = cvt_pk_bf16(src_[8],  src_[9]);  q1_.y = cvt_pk_bf16(src_[10], src_[11]); \
        q1_.z = cvt_pk_bf16(src_[12], src_[13]); q1_.w = cvt_pk_bf16(src_[14], src_[15]); \
        *(uint4*)&Bs[buf_][bD]       = q0_;                                    \
        *(uint4*)&Bs[buf_][bD + 128] = q1_;                                    \
    } while (0)

// MODE 2: steady (DMA t+2, load B t+2, wait vmcnt(18), commit B(t+1), barrier)
// MODE 1: t==NITER-2 (no new loads; wait vmcnt(0), commit B(NITER-1), barrier)
// MODE 0: t==NITER-1 (compute only)
#define BODY(t_, cur_, ARD_, ADMA_, LDst_, CMsrc_, MODE_)                      \
    do {                                                                       \
        bf16x8 af_[4], bf_[4];                                                 \
        _Pragma("unroll")                                                      \
        for (int m_ = 0; m_ < 4; ++m_)                                         \
            af_[m_] = *(const bf16x8*)((ARD_) + (wr * 4 + m_) * 512 + lane * 8); \
        _Pragma("unroll")                                                      \
        for (int n_ = 0; n_ < 4; ++n_)                                         \
            bf_[n_] = *(const bf16x8*)&Bs[cur_][(wc * 4 + n_) * 512 + lane * 8]; \
        FENCE;                                                                 \
        if (MODE_ == 2) DMA_A((t_) + 2, ADMA_);                                \
        FENCE;                                                                 \
        if (MODE_ == 2) LOADB(LDst_, (t_) + 2);                                \
        asm volatile("s_waitcnt lgkmcnt(0)" ::: "memory");                     \
        FENCE;                                                                 \
        _Pragma("unroll")                                                      \
        for (int n_ = 0; n_ < 4; ++n_)                                         \
            _Pragma("unroll")                                                  \
            for (int m_ = 0; m_ < 4; ++m_)                                     \
                acc[m_][n_] = __builtin_amdgcn_mfma_f32_16x16x32_bf16(         \
                    af_[m_], bf_[n_], acc[m_][n_], 0, 0, 0);                   \
        FENCE;                                                                 \
        if (MODE_ == 2) { asm volatile("s_waitcnt vmcnt(18)" ::: "memory"); }  \
        else if (MODE_ == 1) { asm volatile("s_waitcnt vmcnt(0)" ::: "memory"); } \
        if (MODE_ >= 1) {                                                      \
            COMMITB(CMsrc_, (cur_) ^ 1);                                       \
            asm volatile("s_waitcnt lgkmcnt(0)" ::: "memory");                 \
            __builtin_amdgcn_s_barrier();                                      \
            FENCE;                                                             \
        }                                                                      \
    } while (0)

    // prologue: DMA(0), B(0); DMA(1), B(1); wait first 18 -> commit B(0)
    DMA_A(0, A0);
    FENCE;
    LOADB(bvA, 0);
    FENCE;
    DMA_A(1, A1);
    FENCE;
    LOADB(bvB, 1);
    asm volatile("s_waitcnt vmcnt(18)" ::: "memory");   // DMA(0)+B(0) done
    FENCE;
    COMMITB(bvA, 0);
    asm volatile("s_waitcnt lgkmcnt(0)" ::: "memory");
    __builtin_amdgcn_s_barrier();
    FENCE;

    // invariant at loop head: A0=buf(t%3), A1=buf(t+1), A2=buf(t+2)
#pragma unroll 1
    for (int t = 0; t + 4 <= NITER; t += 2) {
        BODY(t,     0, A0, A2, bvA, bvB, 2);   // read t,  DMA t+2 -> A2
        BODY(t + 1, 1, A1, A0, bvB, bvA, 2);   // read t+1, DMA t+3 -> A0
        unsigned short* tr_ = A2; A2 = A1; A1 = A0; A0 = tr_;
    }
    BODY(NITER - 2, 0, A0, A2, bvA, bvB, 1);
    BODY(NITER - 1, 1, A1, A2, bvB, bvA, 0);

#undef BODY
#undef COMMITB
#undef DMA_A
#undef LOADB
#undef FENCE

    // epilogue: C/D layout col = lane&15 (=r), row = 4*(lane>>4) (=4g) + reg
#pragma unroll
    for (int m = 0; m < 4; ++m) {
#pragma unroll
        for (int j = 0; j < 4; ++j) {
            int lrow = mt * 128 + wr * 64 + m * 16 + g * 4 + j;
            if (lrow < ne) {
                int slot = base + lrow;
#pragma unroll
                for (int n = 0; n < 4; ++n) {
                    int col = n0 + wc * 64 + n * 16 + r;
                    if constexpr (LAYER == 1) {
                        float v = acc[m][n][j] + bias[(size_t)e * NT + col];
                        v = fmaxf(v, 0.0f);
                        H[(size_t)slot * HDIM + col] = f2bf(v);
                    } else {
                        atomicAdd(&out[(size_t)perm[slot] * ODIM + col],
                                  gate_s[slot] * acc[m][n][j]);
                    }
                }
            }
        }
    }
}

// ---------------- launch ----------------
extern "C" void kernel_launch(void* const* d_in, const int* in_sizes, int n_in,
                              void* d_out, int out_size, void* d_ws, size_t ws_size,
                              hipStream_t stream) {
    const float* x  = (const float*)d_in[0];
    const float* Wg = (const float*)d_in[1];
    const float* bg = (const float*)d_in[2];
    const float* W1 = (const float*)d_in[3];
    const float* b1 = (const float*)d_in[4];
    const float* W2 = (const float*)d_in[5];
    const float* b2 = (const float*)d_in[6];
    float* out = (float*)d_out;

    char* ws = (char*)d_ws;
    int*   cnt    = (int*)(ws + 0);
    int*   offs   = (int*)(ws + 64);
    int*   mc     = (int*)(ws + 128);
    int*   g1s    = (int*)(ws + 256);              // 480 ints
    int*   g2s    = (int*)(ws + 2304);             // 48 ints
    int*   tbl1   = (int*)(ws + 3072);             // 2816 ints
    int*   tbl2   = (int*)(ws + 14336);            // 1344 ints
    int*   top_e  = (int*)(ws + 19712);
    int*   rnk    = (int*)(ws + 19712 + 16384);
    float* top_p  = (float*)(ws + 19712 + 2 * 16384);
    int*   perm   = (int*)(ws + 19712 + 3 * 16384);
    float* gate_s = (float*)(ws + 19712 + 4 * 16384);
    unsigned short* Xg = (unsigned short*)(ws + 101632);
    unsigned short* H  = (unsigned short*)(ws + 101632 + (size_t)N_TOK * DIM * 2);
    // total ws: ~69.3 MB

    moe_init<<<1, 64, 0, stream>>>(cnt);
    moe_gating<<<N_TOK / 4, 256, 0, stream>>>(x, Wg, bg, cnt, top_e, rnk, top_p);
    moe_scan<<<1, 64, 0, stream>>>(cnt, offs, mc, g1s, g2s);
    moe_fill<<<(G1GRID + G2GRID + 255) / 256, 256, 0, stream>>>(mc, g1s, g2s, tbl1, tbl2);
    moe_mkperm<<<N_TOK / 256, 256, 0, stream>>>(top_e, rnk, top_p, offs, perm, gate_s);
    moe_gather<<<N_TOK, 256, 0, stream>>>(x, perm, Xg);
    moe_initout<<<N_TOK, 256, 0, stream>>>(top_e, top_p, b2, out);

    moe_gemm<1><<<G1GRID, 256, 0, stream>>>(Xg, W1, b1, cnt, offs, perm, gate_s, tbl1, H, out);
    moe_gemm<2><<<G2GRID, 256, 0, stream>>>(H, W2, b2, cnt, offs, perm, gate_s, tbl2, H, out);
}